// Round 12
// baseline (186.203 us; speedup 1.0000x reference)
//
#include <hip/hip_runtime.h>
#include <cstdint>

// Problem constants
static constexpr int LSZ = 2304;   // H*W
static constexpr int CBS = 96;     // d_model
static constexpr int DIN = 192;    // d_inner
static constexpr int NST = 16;     // d_state
static constexpr int HHT = 48;
static constexpr int WWD = 48;
static constexpr int CHN = 16;     // chunks for parallel scan
static constexpr int CHL = 144;    // LSZ / CHN  (divisible by 48)

// ---------------- workspace layout (floats) ----------------
static constexpr size_t OFF_XCONV = 0;          // 884736
static constexpr size_t OFF_SILUZ = 884736;     // 884736
static constexpr size_t OFF_XC    = 1769472;    // 884736
static constexpr size_t OFF_XCT   = 2654208;    // 884736
static constexpr size_t OFF_BCT   = 3686400;    // 8 * 2304 * 32 = 589824  (B n=0..15, C n=16..31)
static constexpr size_t OFF_DELTA = 4276224;    // 1536 * 2304 = 3538944
static constexpr size_t OFF_YK    = 7815168;    // 3538944
static constexpr size_t OFF_WT    = 11796480;   // 73728

__device__ __forceinline__ float f4get(const float4& v, int i) {
    return i == 0 ? v.x : i == 1 ? v.y : i == 2 ? v.z : v.w;
}

// rotate-reduce sum over each aligned 16-lane group (all lanes get the sum)
__device__ __forceinline__ float rotadd16(float v) {
    int m;
    m = __builtin_amdgcn_update_dpp(0, __float_as_int(v), 0x128, 0xf, 0xf, false); v += __int_as_float(m); // ror8
    m = __builtin_amdgcn_update_dpp(0, __float_as_int(v), 0x124, 0xf, 0xf, false); v += __int_as_float(m); // ror4
    m = __builtin_amdgcn_update_dpp(0, __float_as_int(v), 0x122, 0xf, 0xf, false); v += __int_as_float(m); // ror2
    m = __builtin_amdgcn_update_dpp(0, __float_as_int(v), 0x121, 0xf, 0xf, false); v += __int_as_float(m); // ror1
    return v;
}

// ---------------- prep: weight transposes (quad-interleaved layouts) ----------------
// Wt4 : [c/4][384][4]  (36864)   WoT4: [d2/4][96][4] (18432)
// W1T4: [j/4][96][4]   (9216)    W2T4: [j/4][96][4]  (9216)
__global__ __launch_bounds__(256) void kPrep(const float* __restrict__ Wp,
    const float* __restrict__ Wo, const float* __restrict__ W1,
    const float* __restrict__ W2, float* __restrict__ wt) {
    int e = blockIdx.x * 256 + threadIdx.x;
    if (e < 36864) {
        int cq = e / 1536, rem = e % 1536; int t = rem >> 2, q = rem & 3;
        int c = 4 * cq + q;
        wt[e] = Wp[t * 96 + c];
    } else if (e < 55296) {
        int e2 = e - 36864;
        int dq = e2 / 384, rem = e2 % 384; int tp = rem >> 2, q = rem & 3;
        int d2 = 4 * dq + q;
        wt[e] = Wo[tp * 192 + d2];
    } else if (e < 64512) {
        int e3 = e - 55296;
        int jq = e3 / 384, rem = e3 % 384; int tp = rem >> 2, q = rem & 3;
        int j = 4 * jq + q;
        wt[e] = W1[tp * 96 + j];
    } else if (e < 73728) {
        int e3 = e - 64512;
        int jq = e3 / 384, rem = e3 % 384; int tp = rem >> 2, q = rem & 3;
        int j = 4 * jq + q;
        wt[e] = W2[tp * 96 + j];
    }
}

// ---------------- A: LN1 + in_proj (768 thr, split-c + LDS reduce; wave-parallel LN; quad weights) ----------------
__global__ __launch_bounds__(768) void kA(const float* __restrict__ x,
    const float* __restrict__ ln1w, const float* __restrict__ ln1b,
    const float* __restrict__ Wt, float* __restrict__ xconv, float* __restrict__ siluz) {
    int blk = blockIdx.x; int b = blk / 144; int s0 = (blk % 144) * 16;
    int tid = threadIdx.x;
    __shared__ float xln[96][20];
    __shared__ float redA[384][17];
    __shared__ float mu16[16], ir16[16];
#pragma unroll
    for (int it = 0; it < 2; ++it) {
        int e = it * 768 + tid; int c = e >> 4, si = e & 15;
        xln[c][si] = x[((size_t)b * CBS + c) * LSZ + s0 + si];
    }
    __syncthreads();
    if (tid < 64) {
        int si = tid & 15, g = tid >> 4;
        float s1 = 0.f, s2 = 0.f;
        for (int c = g; c < 96; c += 4) { float v = xln[c][si]; s1 += v; s2 += v * v; }
        s1 += __shfl_xor(s1, 16); s2 += __shfl_xor(s2, 16);
        s1 += __shfl_xor(s1, 32); s2 += __shfl_xor(s2, 32);
        if (g == 0) {
            float mu = s1 * (1.f / 96.f);
            mu16[si] = mu; ir16[si] = rsqrtf(s2 * (1.f / 96.f) - mu * mu + 1e-5f);
        }
    }
    __syncthreads();
#pragma unroll
    for (int it = 0; it < 2; ++it) {
        int e = it * 768 + tid; int c = e >> 4, si = e & 15;
        xln[c][si] = (xln[c][si] - mu16[si]) * ir16[si] * ln1w[c] + ln1b[c];
    }
    __syncthreads();
    int t = tid % 384, cg = tid / 384;
    float acc[16];
#pragma unroll
    for (int i = 0; i < 16; ++i) acc[i] = 0.f;
    const float4* Wt4 = (const float4*)Wt;
    for (int cq = cg * 12; cq < cg * 12 + 12; ++cq) {
        float4 wv = Wt4[cq * 384 + t];
#pragma unroll
        for (int i = 0; i < 16; ++i) {
            acc[i] = fmaf(wv.x, xln[4 * cq + 0][i],
                     fmaf(wv.y, xln[4 * cq + 1][i],
                     fmaf(wv.z, xln[4 * cq + 2][i],
                     fmaf(wv.w, xln[4 * cq + 3][i], acc[i]))));
        }
    }
    if (cg == 1) {
#pragma unroll
        for (int i = 0; i < 16; ++i) redA[t][i] = acc[i];
    }
    __syncthreads();
    if (cg == 0) {
#pragma unroll
        for (int i = 0; i < 16; ++i) acc[i] += redA[t][i];
        if (t < DIN) {
            size_t base = ((size_t)b * DIN + t) * LSZ + s0;
#pragma unroll
            for (int q = 0; q < 4; ++q) {
                float4 v = make_float4(acc[4 * q], acc[4 * q + 1], acc[4 * q + 2], acc[4 * q + 3]);
                *(float4*)(xconv + base + 4 * q) = v;
            }
        } else {
            int tz = t - DIN;
#pragma unroll
            for (int si = 0; si < 16; ++si) {
                float z = acc[si];
                siluz[((size_t)b * LSZ + s0 + si) * DIN + tz] = z / (1.f + __expf(-z));
            }
        }
    }
}

// ---------------- B: depthwise 3x3 conv + bias + SiLU, one block per (b,d) plane ----------------
__global__ __launch_bounds__(256) void kB(const float* __restrict__ xconv,
    const float* __restrict__ cw, const float* __restrict__ cb,
    float* __restrict__ xc, float* __restrict__ xcT) {
    int bd = blockIdx.x;               // b*DIN + d
    int d = bd % DIN;
    int tid = threadIdx.x;
    __shared__ float inp[2304];
    __shared__ float outp[48 * 49];
    const float* src = xconv + (size_t)bd * LSZ;
#pragma unroll
    for (int i = 0; i < 9; ++i) inp[i * 256 + tid] = src[i * 256 + tid];
    float w0 = cw[d * 9 + 0], w1 = cw[d * 9 + 1], w2 = cw[d * 9 + 2];
    float w3 = cw[d * 9 + 3], w4 = cw[d * 9 + 4], w5 = cw[d * 9 + 5];
    float w6 = cw[d * 9 + 6], w7 = cw[d * 9 + 7], w8 = cw[d * 9 + 8];
    float bias = cb[d];
    __syncthreads();
#pragma unroll
    for (int i = 0; i < 9; ++i) {
        int s = i * 256 + tid; int h = s / 48, w = s % 48;
        float acc = bias;
        bool hn = h > 0, hp = h < 47, wn = w > 0, wp = w < 47;
        if (hn) {
            if (wn) acc = fmaf(inp[s - 49], w0, acc);
            acc = fmaf(inp[s - 48], w1, acc);
            if (wp) acc = fmaf(inp[s - 47], w2, acc);
        }
        if (wn) acc = fmaf(inp[s - 1], w3, acc);
        acc = fmaf(inp[s], w4, acc);
        if (wp) acc = fmaf(inp[s + 1], w5, acc);
        if (hp) {
            if (wn) acc = fmaf(inp[s + 47], w6, acc);
            acc = fmaf(inp[s + 48], w7, acc);
            if (wp) acc = fmaf(inp[s + 49], w8, acc);
        }
        float r = acc / (1.f + __expf(-acc));
        xc[(size_t)bd * LSZ + s] = r;
        outp[h * 49 + w] = r;
    }
    __syncthreads();
#pragma unroll
    for (int i = 0; i < 9; ++i) {
        int p = i * 256 + tid;          // p = w*48 + h
        int w = p / 48, h = p % 48;
        xcT[(size_t)bd * LSZ + p] = outp[h * 49 + w];
    }
}

// ---------------- C: x_proj + BCt pack + dt_proj + softplus ----------------
__global__ __launch_bounds__(256) void kC(const float* __restrict__ xc,
    const float* __restrict__ xcT, const float* __restrict__ xpw,
    const float* __restrict__ dtw, const float* __restrict__ dtb,
    float* __restrict__ BCt, float* __restrict__ delta) {
    int blk = blockIdx.x; int lt = blk % 36; int k = (blk / 36) & 3; int b = blk / 144;
    int l0 = lt * 64;
    int bk = b * 4 + k;
    __shared__ float xs[DIN][64];
    __shared__ float stage[64][33];
    __shared__ float dtrL[6][64];
    __shared__ float wsh[DIN * 6];
    __shared__ float bshL[DIN];
    const float* src = ((k & 1) ? xcT : xc) + (size_t)b * DIN * LSZ;
    bool fwd = (k < 2);
    int tid = threadIdx.x;
    for (int e = tid; e < 1152; e += 256) wsh[e] = dtw[k * 1152 + e];
    if (tid < DIN) bshL[tid] = dtb[k * DIN + tid];
#pragma unroll
    for (int i = 0; i < 48; ++i) {
        int e = i * 256 + tid; int d = e >> 6, ll = e & 63;
        int l = l0 + ll; int sl = fwd ? l : (LSZ - 1 - l);
        xs[d][ll] = src[(size_t)d * LSZ + sl];
    }
    __syncthreads();
    int c0 = tid >> 6, ll = tid & 63;
    float acc[10];
#pragma unroll
    for (int j = 0; j < 10; ++j) acc[j] = 0.f;
    for (int d0 = 0; d0 < DIN; d0 += 16) {
        float xv[16];
#pragma unroll
        for (int i = 0; i < 16; ++i) xv[i] = xs[d0 + i][ll];
#pragma unroll
        for (int j = 0; j < 10; ++j) {
            int c = j * 4 + c0;
            if (c < 38) {
                const float4* wr = (const float4*)(xpw + ((size_t)(k * 38 + c)) * DIN + d0);
                float4 q0 = wr[0], q1 = wr[1], q2 = wr[2], q3 = wr[3];
                acc[j] += xv[0] * q0.x + xv[1] * q0.y + xv[2] * q0.z + xv[3] * q0.w
                        + xv[4] * q1.x + xv[5] * q1.y + xv[6] * q1.z + xv[7] * q1.w
                        + xv[8] * q2.x + xv[9] * q2.y + xv[10] * q2.z + xv[11] * q2.w
                        + xv[12] * q3.x + xv[13] * q3.y + xv[14] * q3.z + xv[15] * q3.w;
            }
        }
    }
#pragma unroll
    for (int j = 0; j < 10; ++j) {
        int c = j * 4 + c0;
        if (c < 6) {
            dtrL[c][ll] = acc[j];
        } else if (c < 38) {
            int n2 = (c < 22) ? (c - 6) : (16 + c - 22);
            stage[ll][n2] = acc[j];
        }
    }
    __syncthreads();
    // coalesced write-out: BCt rows l0..l0+63, 32 floats each (contiguous 8KB)
    float* dst = BCt + ((size_t)bk * LSZ + l0) * 32;
#pragma unroll
    for (int it = 0; it < 8; ++it) {
        int e = it * 256 + tid;
        int l = e >> 5, n2 = e & 31;
        dst[e] = stage[l][n2];
    }
    // dt_proj + softplus -> delta
    int dsub = tid >> 6;
    float dr[6];
#pragma unroll
    for (int r = 0; r < 6; ++r) dr[r] = dtrL[r][ll];
    for (int j = 0; j < 48; ++j) {
        int d = j * 4 + dsub;
        float a2 = bshL[d];
#pragma unroll
        for (int r = 0; r < 6; ++r) a2 = fmaf(dr[r], wsh[d * 6 + r], a2);
        float sp = (a2 > 20.f) ? a2 : log1pf(__expf(a2));
        delta[((size_t)bk * DIN + d) * LSZ + l0 + ll] = sp;
    }
}

// ---------------- D: fused 2-pass chunked scan (FROZEN — round-7 exact) ----------------
__global__ __launch_bounds__(256, 4) void kD(const float* __restrict__ delta,
    const float* __restrict__ xc, const float* __restrict__ xcT,
    const float* __restrict__ BCt, const float* __restrict__ A_log, float* __restrict__ yk) {
    int g = blockIdx.x;                 // bk*192 + d
    int tid = threadIdx.x;
    int n = tid & 15; int c = tid >> 4; // chunk 0..15
    int d = g % DIN; int bk = g / DIN; int k = bk & 3; int b = bk >> 2;
    __shared__ float hfinL[256];
    __shared__ float sumdL[16];
    __shared__ float hinL[256];

    float An2 = -__expf(A_log[((size_t)(k * DIN + d)) * NST + n]) * 1.44269504f;
    const float* ub = ((k & 1) ? xcT : xc) + ((size_t)(b * DIN + d)) * LSZ;
    bool fwd = (k < 2);
    int l0 = c * CHL;
    const float* dp = delta + (size_t)g * LSZ + l0;
    const float* up = fwd ? (ub + l0) : (ub + (LSZ - 4) - l0);
    const float* bc = BCt + ((size_t)bk * LSZ + l0) * 32 + n;   // B at +l*32, C at +l*32+16

    // ---- phase 1: chunk-local scan from h=0; record h_final and sum(delta) ----
    float h = 0.f, sd = 0.f;
    for (int j0 = 0; j0 < CHL; j0 += 4) {
        float4 dv = *(const float4*)(dp + j0);
        float4 uv;
        if (fwd) uv = *(const float4*)(up + j0);
        else { float4 tv = *(const float4*)(up - j0); uv = make_float4(tv.w, tv.z, tv.y, tv.x); }
#pragma unroll
        for (int jj = 0; jj < 4; ++jj) {
            float bn = bc[(j0 + jj) * 32];
            float dl = f4get(dv, jj);
            float da = __builtin_amdgcn_exp2f(dl * An2);
            h = fmaf(da, h, dl * f4get(uv, jj) * bn);
            sd += dl;
        }
    }
    hfinL[tid] = h;
    if (n == 0) sumdL[c] = sd;
    __syncthreads();

    // ---- combine: serial prefix over 16 chunks by one 16-lane group ----
    if (tid < 16) {
        float hh = 0.f;
#pragma unroll
        for (int cc = 0; cc < 16; ++cc) {
            hinL[cc * 16 + tid] = hh;
            hh = fmaf(__builtin_amdgcn_exp2f(An2 * sumdL[cc]), hh, hfinL[cc * 16 + tid]);
        }
    }
    __syncthreads();

    // ---- phase 2: re-scan with h_in; lane n keeps y for l%16==n; coalesced stores ----
    h = hinL[tid];
    float* yo = yk + (size_t)g * LSZ + l0 + n;
    for (int m = 0; m < 9; ++m) {
        float ykeep = 0.f;
        for (int q = 0; q < 4; ++q) {
            int j0 = m * 16 + q * 4;
            float4 dv = *(const float4*)(dp + j0);
            float4 uv;
            if (fwd) uv = *(const float4*)(up + j0);
            else { float4 tv = *(const float4*)(up - j0); uv = make_float4(tv.w, tv.z, tv.y, tv.x); }
#pragma unroll
            for (int jj = 0; jj < 4; ++jj) {
                float bn = bc[(j0 + jj) * 32];
                float cn = bc[(j0 + jj) * 32 + 16];
                float dl = f4get(dv, jj);
                float da = __builtin_amdgcn_exp2f(dl * An2);
                h = fmaf(da, h, dl * f4get(uv, jj) * bn);
                float p = rotadd16(h * cn);
                ykeep = (n == q * 4 + jj) ? p : ykeep;
            }
        }
        yo[m * 16] = ykeep;
    }
}

// ---------------- EF: cross-merge + out_norm + gate + out_proj + residual + LN2 + MLP + proj + sigmoid ----------------
__global__ __launch_bounds__(384) void kEF(const float* __restrict__ yk,
    const float* __restrict__ xc, const float* __restrict__ Dsp,
    const float* __restrict__ siluz, const float* __restrict__ x,
    const float* __restrict__ onw, const float* __restrict__ onb,
    const float* __restrict__ WoT,
    const float* __restrict__ l2w, const float* __restrict__ l2b,
    const float* __restrict__ W1T, const float* __restrict__ b1,
    const float* __restrict__ W2T, const float* __restrict__ b2,
    const float* __restrict__ pw, const float* __restrict__ pb, float* __restrict__ out) {
    int blk = blockIdx.x; int b = blk / 144; int s0 = (blk % 144) * 16;
    int tid = threadIdx.x;
    __shared__ float yl[DIN][17];
    __shared__ float xo[96][17];
    __shared__ float aa[96][17];
    __shared__ float red[384][9];
    __shared__ float mu16[16], ir16[16];
    // ---- fused cross-merge load: all 16 si share the same h-row (s0 16-aligned, 48%16==0) ----
    int h0 = s0 / 48, w0 = s0 % 48;
#pragma unroll
    for (int it = 0; it < 8; ++it) {
        int e = it * 384 + tid; int d = e >> 4, si = e & 15;
        int s = s0 + si;
        int p = (w0 + si) * 48 + h0;
        size_t base = ((size_t)(b * 4) * DIN + d) * LSZ;
        float v0 = yk[base + s];
        float v1 = yk[base + (size_t)DIN * LSZ + p];
        float v2 = yk[base + 2 * (size_t)DIN * LSZ + (2303 - s)];
        float v3 = yk[base + 3 * (size_t)DIN * LSZ + (2303 - p)];
        float Dsum = Dsp[d] + Dsp[DIN + d] + Dsp[2 * DIN + d] + Dsp[3 * DIN + d];
        float xcv = xc[((size_t)(b * DIN + d)) * LSZ + s];
        yl[d][si] = (v0 + v2) + (v1 + v3) + Dsum * xcv;
    }
    __syncthreads();
    if (tid < 64) {
        int si = tid & 15, g = tid >> 4;
        float s1 = 0.f, s2 = 0.f;
        for (int c = g; c < 192; c += 4) { float v = yl[c][si]; s1 += v; s2 += v * v; }
        s1 += __shfl_xor(s1, 16); s2 += __shfl_xor(s2, 16);
        s1 += __shfl_xor(s1, 32); s2 += __shfl_xor(s2, 32);
        if (g == 0) {
            float mu = s1 * (1.f / 192.f);
            mu16[si] = mu; ir16[si] = rsqrtf(s2 * (1.f / 192.f) - mu * mu + 1e-5f);
        }
    }
    __syncthreads();
    {
        int d = tid % 192, sh = tid / 192;
#pragma unroll
        for (int i = 0; i < 8; ++i) {
            int si = sh * 8 + i;
            float v = yl[d][si];
            v = (v - mu16[si]) * ir16[si] * onw[d] + onb[d];
            yl[d][si] = v * siluz[((size_t)b * LSZ + s0 + si) * DIN + d];
        }
    }
    __syncthreads();
    int tp = tid % 96, half = (tid / 96) & 1, kg = tid / 192;
    const float4* WoT4 = (const float4*)WoT;
    const float4* W1T4 = (const float4*)W1T;
    const float4* W2T4 = (const float4*)W2T;
    // ---- out_proj (split d2, quad loads) ----
    {
        float acc[8];
#pragma unroll
        for (int i = 0; i < 8; ++i) acc[i] = 0.f;
        for (int dq = kg * 24; dq < kg * 24 + 24; ++dq) {
            float4 wv = WoT4[dq * 96 + tp];
#pragma unroll
            for (int i = 0; i < 8; ++i) {
                acc[i] = fmaf(wv.x, yl[4 * dq + 0][half * 8 + i],
                         fmaf(wv.y, yl[4 * dq + 1][half * 8 + i],
                         fmaf(wv.z, yl[4 * dq + 2][half * 8 + i],
                         fmaf(wv.w, yl[4 * dq + 3][half * 8 + i], acc[i]))));
            }
        }
#pragma unroll
        for (int i = 0; i < 8; ++i) red[tid][i] = acc[i];
    }
    __syncthreads();
    if (tid < 192) {
#pragma unroll
        for (int i = 0; i < 8; ++i) {
            int si = half * 8 + i;
            xo[tp][si] = x[((size_t)b * CBS + tp) * LSZ + s0 + si] + red[tid][i] + red[tid + 192][i];
        }
    }
    __syncthreads();
    // ---- LN2 ----
    if (tid < 64) {
        int si = tid & 15, g = tid >> 4;
        float s1 = 0.f, s2 = 0.f;
        for (int c = g; c < 96; c += 4) { float v = xo[c][si]; s1 += v; s2 += v * v; }
        s1 += __shfl_xor(s1, 16); s2 += __shfl_xor(s2, 16);
        s1 += __shfl_xor(s1, 32); s2 += __shfl_xor(s2, 32);
        if (g == 0) {
            float mu = s1 * (1.f / 96.f);
            mu16[si] = mu; ir16[si] = rsqrtf(s2 * (1.f / 96.f) - mu * mu + 1e-5f);
        }
    }
    __syncthreads();
#pragma unroll
    for (int it = 0; it < 4; ++it) {
        int e = it * 384 + tid; int si = e / 96, cc = e % 96;
        aa[cc][si] = (xo[cc][si] - mu16[si]) * ir16[si] * l2w[cc] + l2b[cc];
    }
    __syncthreads();
    // ---- MLP fc1 (split j, quad loads) ----
    {
        float acc[8];
#pragma unroll
        for (int i = 0; i < 8; ++i) acc[i] = 0.f;
        for (int jq = kg * 12; jq < kg * 12 + 12; ++jq) {
            float4 wv = W1T4[jq * 96 + tp];
#pragma unroll
            for (int i = 0; i < 8; ++i) {
                acc[i] = fmaf(wv.x, aa[4 * jq + 0][half * 8 + i],
                         fmaf(wv.y, aa[4 * jq + 1][half * 8 + i],
                         fmaf(wv.z, aa[4 * jq + 2][half * 8 + i],
                         fmaf(wv.w, aa[4 * jq + 3][half * 8 + i], acc[i]))));
            }
        }
#pragma unroll
        for (int i = 0; i < 8; ++i) red[tid][i] = acc[i];
    }
    __syncthreads();
    if (tid < 192) {
#pragma unroll
        for (int i = 0; i < 8; ++i) {
            float tv = red[tid][i] + red[tid + 192][i] + b1[tp];
            aa[tp][half * 8 + i] = 0.5f * tv * (1.f + erff(tv * 0.70710678118654752f));
        }
    }
    __syncthreads();
    // ---- MLP fc2 (split j, quad loads) ----
    {
        float acc2[8];
#pragma unroll
        for (int i = 0; i < 8; ++i) acc2[i] = 0.f;
        for (int jq = kg * 12; jq < kg * 12 + 12; ++jq) {
            float4 wv = W2T4[jq * 96 + tp];
#pragma unroll
            for (int i = 0; i < 8; ++i) {
                acc2[i] = fmaf(wv.x, aa[4 * jq + 0][half * 8 + i],
                          fmaf(wv.y, aa[4 * jq + 1][half * 8 + i],
                          fmaf(wv.z, aa[4 * jq + 2][half * 8 + i],
                          fmaf(wv.w, aa[4 * jq + 3][half * 8 + i], acc2[i]))));
            }
        }
#pragma unroll
        for (int i = 0; i < 8; ++i) red[tid][i] = acc2[i];
    }
    __syncthreads();
    if (tid < 192) {
#pragma unroll
        for (int i = 0; i < 8; ++i) {
            float xf = xo[tp][half * 8 + i] + red[tid][i] + red[tid + 192][i] + b2[tp];
            aa[tp][half * 8 + i] = xf * pw[tp];
        }
    }
    __syncthreads();
    if (tid < 64) {
        int si = tid & 15, g = tid >> 4;
        float ss = 0.f;
        for (int c = g; c < 96; c += 4) ss += aa[c][si];
        ss += __shfl_xor(ss, 16);
        ss += __shfl_xor(ss, 32);
        if (g == 0)
            out[(size_t)b * LSZ + s0 + si] = 1.f / (1.f + __expf(-(ss + pb[0])));
    }
}

extern "C" void kernel_launch(void* const* d_in, const int* in_sizes, int n_in,
                              void* d_out, int out_size, void* d_ws, size_t ws_size,
                              hipStream_t stream) {
    const float* x    = (const float*)d_in[0];
    const float* ln1w = (const float*)d_in[1];
    const float* ln1b = (const float*)d_in[2];
    const float* Wp   = (const float*)d_in[3];
    const float* cw   = (const float*)d_in[4];
    const float* cb   = (const float*)d_in[5];
    const float* xpw  = (const float*)d_in[6];
    const float* dtw  = (const float*)d_in[7];
    const float* dtb  = (const float*)d_in[8];
    const float* Alog = (const float*)d_in[9];
    const float* Dsp  = (const float*)d_in[10];
    const float* onw  = (const float*)d_in[11];
    const float* onb  = (const float*)d_in[12];
    const float* Wo   = (const float*)d_in[13];
    const float* l2w  = (const float*)d_in[14];
    const float* l2b  = (const float*)d_in[15];
    const float* W1   = (const float*)d_in[16];
    const float* b1   = (const float*)d_in[17];
    const float* W2   = (const float*)d_in[18];
    const float* b2   = (const float*)d_in[19];
    const float* pw   = (const float*)d_in[20];
    const float* pb   = (const float*)d_in[21];

    float* ws    = (float*)d_ws;
    float* xconv = ws + OFF_XCONV;
    float* siluz = ws + OFF_SILUZ;
    float* xc    = ws + OFF_XC;
    float* xcT   = ws + OFF_XCT;
    float* BCt   = ws + OFF_BCT;
    float* delta = ws + OFF_DELTA;
    float* yk    = ws + OFF_YK;
    float* wt    = ws + OFF_WT;
    float* WoT   = wt + 36864;
    float* W1T   = wt + 55296;
    float* W2T   = wt + 64512;

    kPrep<<<288, 256, 0, stream>>>(Wp, Wo, W1, W2, wt);
    kA<<<288, 768, 0, stream>>>(x, ln1w, ln1b, wt, xconv, siluz);
    kB<<<384, 256, 0, stream>>>(xconv, cw, cb, xc, xcT);
    kC<<<288, 256, 0, stream>>>(xc, xcT, xpw, dtw, dtb, BCt, delta);
    kD<<<1536, 256, 0, stream>>>(delta, xc, xcT, BCt, Alog, yk);
    kEF<<<288, 384, 0, stream>>>(yk, xc, Dsp, siluz, x, onw, onb, WoT,
                                 l2w, l2b, W1T, b1, W2T, b2, pw, pb, (float*)d_out);
}

// Round 13
// 177.799 us; speedup vs baseline: 1.0473x; 1.0473x over previous
//
#include <hip/hip_runtime.h>
#include <cstdint>

// Problem constants
static constexpr int LSZ = 2304;   // H*W
static constexpr int CBS = 96;     // d_model
static constexpr int DIN = 192;    // d_inner
static constexpr int NST = 16;     // d_state
static constexpr int HHT = 48;
static constexpr int WWD = 48;
static constexpr int CHN = 16;     // chunks for parallel scan
static constexpr int CHL = 144;    // LSZ / CHN  (divisible by 48)

// ---------------- workspace layout (floats) ----------------
static constexpr size_t OFF_XCONV = 0;          // 884736 (reused as ym after kB)
static constexpr size_t OFF_SILUZ = 884736;     // 884736
static constexpr size_t OFF_XC    = 1769472;    // 884736
static constexpr size_t OFF_XCT   = 2654208;    // 884736
static constexpr size_t OFF_BCT   = 3686400;    // 8 * 2304 * 32 = 589824  (B n=0..15, C n=16..31)
static constexpr size_t OFF_DELTA = 4276224;    // 1536 * 2304 = 3538944
static constexpr size_t OFF_YK    = 7815168;    // 3538944
static constexpr size_t OFF_WT    = 11796480;   // 73728

__device__ __forceinline__ float f4get(const float4& v, int i) {
    return i == 0 ? v.x : i == 1 ? v.y : i == 2 ? v.z : v.w;
}

// rotate-reduce sum over each aligned 16-lane group (all lanes get the sum)
__device__ __forceinline__ float rotadd16(float v) {
    int m;
    m = __builtin_amdgcn_update_dpp(0, __float_as_int(v), 0x128, 0xf, 0xf, false); v += __int_as_float(m); // ror8
    m = __builtin_amdgcn_update_dpp(0, __float_as_int(v), 0x124, 0xf, 0xf, false); v += __int_as_float(m); // ror4
    m = __builtin_amdgcn_update_dpp(0, __float_as_int(v), 0x122, 0xf, 0xf, false); v += __int_as_float(m); // ror2
    m = __builtin_amdgcn_update_dpp(0, __float_as_int(v), 0x121, 0xf, 0xf, false); v += __int_as_float(m); // ror1
    return v;
}

// ---------------- prep: weight transposes (quad-interleaved layouts) ----------------
// Wt4 : [c/4][384][4]  (36864)   WoT4: [d2/4][96][4] (18432)
// W1T4: [j/4][96][4]   (9216)    W2T4: [j/4][96][4]  (9216)
__global__ __launch_bounds__(256) void kPrep(const float* __restrict__ Wp,
    const float* __restrict__ Wo, const float* __restrict__ W1,
    const float* __restrict__ W2, float* __restrict__ wt) {
    int e = blockIdx.x * 256 + threadIdx.x;
    if (e < 36864) {
        int cq = e / 1536, rem = e % 1536; int t = rem >> 2, q = rem & 3;
        int c = 4 * cq + q;
        wt[e] = Wp[t * 96 + c];
    } else if (e < 55296) {
        int e2 = e - 36864;
        int dq = e2 / 384, rem = e2 % 384; int tp = rem >> 2, q = rem & 3;
        int d2 = 4 * dq + q;
        wt[e] = Wo[tp * 192 + d2];
    } else if (e < 64512) {
        int e3 = e - 55296;
        int jq = e3 / 384, rem = e3 % 384; int tp = rem >> 2, q = rem & 3;
        int j = 4 * jq + q;
        wt[e] = W1[tp * 96 + j];
    } else if (e < 73728) {
        int e3 = e - 64512;
        int jq = e3 / 384, rem = e3 % 384; int tp = rem >> 2, q = rem & 3;
        int j = 4 * jq + q;
        wt[e] = W2[tp * 96 + j];
    }
}

// ---------------- A: LN1 + in_proj (768 thr, split-c + LDS reduce; wave-parallel LN; quad weights) ----------------
__global__ __launch_bounds__(768) void kA(const float* __restrict__ x,
    const float* __restrict__ ln1w, const float* __restrict__ ln1b,
    const float* __restrict__ Wt, float* __restrict__ xconv, float* __restrict__ siluz) {
    int blk = blockIdx.x; int b = blk / 144; int s0 = (blk % 144) * 16;
    int tid = threadIdx.x;
    __shared__ float xln[96][20];
    __shared__ float redA[384][17];
    __shared__ float mu16[16], ir16[16];
#pragma unroll
    for (int it = 0; it < 2; ++it) {
        int e = it * 768 + tid; int c = e >> 4, si = e & 15;
        xln[c][si] = x[((size_t)b * CBS + c) * LSZ + s0 + si];
    }
    __syncthreads();
    if (tid < 64) {
        int si = tid & 15, g = tid >> 4;
        float s1 = 0.f, s2 = 0.f;
        for (int c = g; c < 96; c += 4) { float v = xln[c][si]; s1 += v; s2 += v * v; }
        s1 += __shfl_xor(s1, 16); s2 += __shfl_xor(s2, 16);
        s1 += __shfl_xor(s1, 32); s2 += __shfl_xor(s2, 32);
        if (g == 0) {
            float mu = s1 * (1.f / 96.f);
            mu16[si] = mu; ir16[si] = rsqrtf(s2 * (1.f / 96.f) - mu * mu + 1e-5f);
        }
    }
    __syncthreads();
#pragma unroll
    for (int it = 0; it < 2; ++it) {
        int e = it * 768 + tid; int c = e >> 4, si = e & 15;
        xln[c][si] = (xln[c][si] - mu16[si]) * ir16[si] * ln1w[c] + ln1b[c];
    }
    __syncthreads();
    int t = tid % 384, cg = tid / 384;
    float acc[16];
#pragma unroll
    for (int i = 0; i < 16; ++i) acc[i] = 0.f;
    const float4* Wt4 = (const float4*)Wt;
    for (int cq = cg * 12; cq < cg * 12 + 12; ++cq) {
        float4 wv = Wt4[cq * 384 + t];
#pragma unroll
        for (int i = 0; i < 16; ++i) {
            acc[i] = fmaf(wv.x, xln[4 * cq + 0][i],
                     fmaf(wv.y, xln[4 * cq + 1][i],
                     fmaf(wv.z, xln[4 * cq + 2][i],
                     fmaf(wv.w, xln[4 * cq + 3][i], acc[i]))));
        }
    }
    if (cg == 1) {
#pragma unroll
        for (int i = 0; i < 16; ++i) redA[t][i] = acc[i];
    }
    __syncthreads();
    if (cg == 0) {
#pragma unroll
        for (int i = 0; i < 16; ++i) acc[i] += redA[t][i];
        if (t < DIN) {
            size_t base = ((size_t)b * DIN + t) * LSZ + s0;
#pragma unroll
            for (int q = 0; q < 4; ++q) {
                float4 v = make_float4(acc[4 * q], acc[4 * q + 1], acc[4 * q + 2], acc[4 * q + 3]);
                *(float4*)(xconv + base + 4 * q) = v;
            }
        } else {
            int tz = t - DIN;
#pragma unroll
            for (int si = 0; si < 16; ++si) {
                float z = acc[si];
                siluz[((size_t)b * LSZ + s0 + si) * DIN + tz] = z / (1.f + __expf(-z));
            }
        }
    }
}

// ---------------- B: depthwise conv, 2 planes per 512-thr block (grid 192, balanced; LDS 37KB) ----------------
__global__ __launch_bounds__(512) void kB(const float* __restrict__ xconv,
    const float* __restrict__ cw, const float* __restrict__ cb,
    float* __restrict__ xc, float* __restrict__ xcT) {
    int grp = threadIdx.x >> 8;
    int tid = threadIdx.x & 255;
    int bd = blockIdx.x * 2 + grp;      // < 384
    int d = bd % DIN;
    __shared__ float inp[2][2304];
    __shared__ float outp[2][48 * 49];
    const float* src = xconv + (size_t)bd * LSZ;
#pragma unroll
    for (int i = 0; i < 9; ++i) inp[grp][i * 256 + tid] = src[i * 256 + tid];
    float w0 = cw[d * 9 + 0], w1 = cw[d * 9 + 1], w2 = cw[d * 9 + 2];
    float w3 = cw[d * 9 + 3], w4 = cw[d * 9 + 4], w5 = cw[d * 9 + 5];
    float w6 = cw[d * 9 + 6], w7 = cw[d * 9 + 7], w8 = cw[d * 9 + 8];
    float bias = cb[d];
    __syncthreads();
#pragma unroll
    for (int i = 0; i < 9; ++i) {
        int s = i * 256 + tid; int h = s / 48, w = s % 48;
        float acc = bias;
        bool hn = h > 0, hp = h < 47, wn = w > 0, wp = w < 47;
        if (hn) {
            if (wn) acc = fmaf(inp[grp][s - 49], w0, acc);
            acc = fmaf(inp[grp][s - 48], w1, acc);
            if (wp) acc = fmaf(inp[grp][s - 47], w2, acc);
        }
        if (wn) acc = fmaf(inp[grp][s - 1], w3, acc);
        acc = fmaf(inp[grp][s], w4, acc);
        if (wp) acc = fmaf(inp[grp][s + 1], w5, acc);
        if (hp) {
            if (wn) acc = fmaf(inp[grp][s + 47], w6, acc);
            acc = fmaf(inp[grp][s + 48], w7, acc);
            if (wp) acc = fmaf(inp[grp][s + 49], w8, acc);
        }
        float r = acc / (1.f + __expf(-acc));
        xc[(size_t)bd * LSZ + s] = r;
        outp[grp][h * 49 + w] = r;
    }
    __syncthreads();
#pragma unroll
    for (int i = 0; i < 9; ++i) {
        int p = i * 256 + tid;          // p = w*48 + h
        int w = p / 48, h = p % 48;
        xcT[(size_t)bd * LSZ + p] = outp[grp][h * 49 + w];
    }
}

// ---------------- C: x_proj + BCt pack + dt_proj + softplus ----------------
__global__ __launch_bounds__(256) void kC(const float* __restrict__ xc,
    const float* __restrict__ xcT, const float* __restrict__ xpw,
    const float* __restrict__ dtw, const float* __restrict__ dtb,
    float* __restrict__ BCt, float* __restrict__ delta) {
    int blk = blockIdx.x; int lt = blk % 36; int k = (blk / 36) & 3; int b = blk / 144;
    int l0 = lt * 64;
    int bk = b * 4 + k;
    __shared__ float xs[DIN][64];
    __shared__ float stage[64][33];
    __shared__ float dtrL[6][64];
    __shared__ float wsh[DIN * 6];
    __shared__ float bshL[DIN];
    const float* src = ((k & 1) ? xcT : xc) + (size_t)b * DIN * LSZ;
    bool fwd = (k < 2);
    int tid = threadIdx.x;
    for (int e = tid; e < 1152; e += 256) wsh[e] = dtw[k * 1152 + e];
    if (tid < DIN) bshL[tid] = dtb[k * DIN + tid];
#pragma unroll
    for (int i = 0; i < 48; ++i) {
        int e = i * 256 + tid; int d = e >> 6, ll = e & 63;
        int l = l0 + ll; int sl = fwd ? l : (LSZ - 1 - l);
        xs[d][ll] = src[(size_t)d * LSZ + sl];
    }
    __syncthreads();
    int c0 = tid >> 6, ll = tid & 63;
    float acc[10];
#pragma unroll
    for (int j = 0; j < 10; ++j) acc[j] = 0.f;
    for (int d0 = 0; d0 < DIN; d0 += 16) {
        float xv[16];
#pragma unroll
        for (int i = 0; i < 16; ++i) xv[i] = xs[d0 + i][ll];
#pragma unroll
        for (int j = 0; j < 10; ++j) {
            int c = j * 4 + c0;
            if (c < 38) {
                const float4* wr = (const float4*)(xpw + ((size_t)(k * 38 + c)) * DIN + d0);
                float4 q0 = wr[0], q1 = wr[1], q2 = wr[2], q3 = wr[3];
                acc[j] += xv[0] * q0.x + xv[1] * q0.y + xv[2] * q0.z + xv[3] * q0.w
                        + xv[4] * q1.x + xv[5] * q1.y + xv[6] * q1.z + xv[7] * q1.w
                        + xv[8] * q2.x + xv[9] * q2.y + xv[10] * q2.z + xv[11] * q2.w
                        + xv[12] * q3.x + xv[13] * q3.y + xv[14] * q3.z + xv[15] * q3.w;
            }
        }
    }
#pragma unroll
    for (int j = 0; j < 10; ++j) {
        int c = j * 4 + c0;
        if (c < 6) {
            dtrL[c][ll] = acc[j];
        } else if (c < 38) {
            int n2 = (c < 22) ? (c - 6) : (16 + c - 22);
            stage[ll][n2] = acc[j];
        }
    }
    __syncthreads();
    // coalesced write-out: BCt rows l0..l0+63, 32 floats each (contiguous 8KB)
    float* dst = BCt + ((size_t)bk * LSZ + l0) * 32;
#pragma unroll
    for (int it = 0; it < 8; ++it) {
        int e = it * 256 + tid;
        int l = e >> 5, n2 = e & 31;
        dst[e] = stage[l][n2];
    }
    // dt_proj + softplus -> delta
    int dsub = tid >> 6;
    float dr[6];
#pragma unroll
    for (int r = 0; r < 6; ++r) dr[r] = dtrL[r][ll];
    for (int j = 0; j < 48; ++j) {
        int d = j * 4 + dsub;
        float a2 = bshL[d];
#pragma unroll
        for (int r = 0; r < 6; ++r) a2 = fmaf(dr[r], wsh[d * 6 + r], a2);
        float sp = (a2 > 20.f) ? a2 : log1pf(__expf(a2));
        delta[((size_t)bk * DIN + d) * LSZ + l0 + ll] = sp;
    }
}

// ---------------- D: fused 2-pass chunked scan (FROZEN — round-7 exact) ----------------
__global__ __launch_bounds__(256, 4) void kD(const float* __restrict__ delta,
    const float* __restrict__ xc, const float* __restrict__ xcT,
    const float* __restrict__ BCt, const float* __restrict__ A_log, float* __restrict__ yk) {
    int g = blockIdx.x;                 // bk*192 + d
    int tid = threadIdx.x;
    int n = tid & 15; int c = tid >> 4; // chunk 0..15
    int d = g % DIN; int bk = g / DIN; int k = bk & 3; int b = bk >> 2;
    __shared__ float hfinL[256];
    __shared__ float sumdL[16];
    __shared__ float hinL[256];

    float An2 = -__expf(A_log[((size_t)(k * DIN + d)) * NST + n]) * 1.44269504f;
    const float* ub = ((k & 1) ? xcT : xc) + ((size_t)(b * DIN + d)) * LSZ;
    bool fwd = (k < 2);
    int l0 = c * CHL;
    const float* dp = delta + (size_t)g * LSZ + l0;
    const float* up = fwd ? (ub + l0) : (ub + (LSZ - 4) - l0);
    const float* bc = BCt + ((size_t)bk * LSZ + l0) * 32 + n;   // B at +l*32, C at +l*32+16

    // ---- phase 1: chunk-local scan from h=0; record h_final and sum(delta) ----
    float h = 0.f, sd = 0.f;
    for (int j0 = 0; j0 < CHL; j0 += 4) {
        float4 dv = *(const float4*)(dp + j0);
        float4 uv;
        if (fwd) uv = *(const float4*)(up + j0);
        else { float4 tv = *(const float4*)(up - j0); uv = make_float4(tv.w, tv.z, tv.y, tv.x); }
#pragma unroll
        for (int jj = 0; jj < 4; ++jj) {
            float bn = bc[(j0 + jj) * 32];
            float dl = f4get(dv, jj);
            float da = __builtin_amdgcn_exp2f(dl * An2);
            h = fmaf(da, h, dl * f4get(uv, jj) * bn);
            sd += dl;
        }
    }
    hfinL[tid] = h;
    if (n == 0) sumdL[c] = sd;
    __syncthreads();

    // ---- combine: serial prefix over 16 chunks by one 16-lane group ----
    if (tid < 16) {
        float hh = 0.f;
#pragma unroll
        for (int cc = 0; cc < 16; ++cc) {
            hinL[cc * 16 + tid] = hh;
            hh = fmaf(__builtin_amdgcn_exp2f(An2 * sumdL[cc]), hh, hfinL[cc * 16 + tid]);
        }
    }
    __syncthreads();

    // ---- phase 2: re-scan with h_in; lane n keeps y for l%16==n; coalesced stores ----
    h = hinL[tid];
    float* yo = yk + (size_t)g * LSZ + l0 + n;
    for (int m = 0; m < 9; ++m) {
        float ykeep = 0.f;
        for (int q = 0; q < 4; ++q) {
            int j0 = m * 16 + q * 4;
            float4 dv = *(const float4*)(dp + j0);
            float4 uv;
            if (fwd) uv = *(const float4*)(up + j0);
            else { float4 tv = *(const float4*)(up - j0); uv = make_float4(tv.w, tv.z, tv.y, tv.x); }
#pragma unroll
            for (int jj = 0; jj < 4; ++jj) {
                float bn = bc[(j0 + jj) * 32];
                float cn = bc[(j0 + jj) * 32 + 16];
                float dl = f4get(dv, jj);
                float da = __builtin_amdgcn_exp2f(dl * An2);
                h = fmaf(da, h, dl * f4get(uv, jj) * bn);
                float p = rotadd16(h * cn);
                ykeep = (n == q * 4 + jj) ? p : ykeep;
            }
        }
        yo[m * 16] = ykeep;
    }
}

// ---------------- M: cross-merge 4 directions + D*u term -> ym[b][d][s] (48x49 padded LDS) ----------------
__global__ __launch_bounds__(256) void kM(const float* __restrict__ yk,
    const float* __restrict__ xc, const float* __restrict__ Dsp, float* __restrict__ ym) {
    int blk = blockIdx.x;               // b*192 + d
    int b = blk / DIN; int d = blk % DIN;
    int tid = threadIdx.x;
    __shared__ float buf[4][48 * 49];
    float Dsum = Dsp[d] + Dsp[DIN + d] + Dsp[2 * DIN + d] + Dsp[3 * DIN + d];
#pragma unroll
    for (int kk = 0; kk < 4; ++kk) {
        const float* src = yk + ((size_t)((b * 4 + kk) * DIN + d)) * LSZ;
#pragma unroll
        for (int i = 0; i < 9; ++i) {
            int s = i * 256 + tid;
            buf[kk][s + s / 48] = src[s];          // element (h,w) at h*49+w
        }
    }
    __syncthreads();
    const float* xrow = xc + ((size_t)(b * DIN + d)) * LSZ;
    float* dst = ym + ((size_t)blk) * LSZ;
#pragma unroll
    for (int i = 0; i < 9; ++i) {
        int s = i * 256 + tid; int hh = s / 48, ww = s % 48;
        float v0 = buf[0][hh * 49 + ww];
        float v2 = buf[2][(47 - hh) * 49 + (47 - ww)];
        float v1 = buf[1][ww * 49 + hh];
        float v3 = buf[3][(47 - ww) * 49 + (47 - hh)];
        dst[s] = v0 + v2 + v1 + v3 + Dsum * xrow[s];
    }
}

// ---------------- EF: fused epilogue (384 thr; wave-parallel LNs; quad weights) ----------------
__global__ __launch_bounds__(384) void kEF(const float* __restrict__ ym,
    const float* __restrict__ siluz, const float* __restrict__ x,
    const float* __restrict__ onw, const float* __restrict__ onb,
    const float* __restrict__ WoT,
    const float* __restrict__ l2w, const float* __restrict__ l2b,
    const float* __restrict__ W1T, const float* __restrict__ b1,
    const float* __restrict__ W2T, const float* __restrict__ b2,
    const float* __restrict__ pw, const float* __restrict__ pb, float* __restrict__ out) {
    int blk = blockIdx.x; int b = blk / 144; int s0 = (blk % 144) * 16;
    int tid = threadIdx.x;
    __shared__ float yl[DIN][17];
    __shared__ float xo[96][17];
    __shared__ float aa[96][17];
    __shared__ float red[384][9];
    __shared__ float mu16[16], ir16[16];
    // ---- load merged y tile ----
#pragma unroll
    for (int it = 0; it < 8; ++it) {
        int e = it * 384 + tid; int d = e >> 4, si = e & 15;
        yl[d][si] = ym[((size_t)(b * DIN + d)) * LSZ + s0 + si];
    }
    __syncthreads();
    if (tid < 64) {
        int si = tid & 15, g = tid >> 4;
        float s1 = 0.f, s2 = 0.f;
        for (int c = g; c < 192; c += 4) { float v = yl[c][si]; s1 += v; s2 += v * v; }
        s1 += __shfl_xor(s1, 16); s2 += __shfl_xor(s2, 16);
        s1 += __shfl_xor(s1, 32); s2 += __shfl_xor(s2, 32);
        if (g == 0) {
            float mu = s1 * (1.f / 192.f);
            mu16[si] = mu; ir16[si] = rsqrtf(s2 * (1.f / 192.f) - mu * mu + 1e-5f);
        }
    }
    __syncthreads();
    {
        int d = tid % 192, sh = tid / 192;
#pragma unroll
        for (int i = 0; i < 8; ++i) {
            int si = sh * 8 + i;
            float v = yl[d][si];
            v = (v - mu16[si]) * ir16[si] * onw[d] + onb[d];
            yl[d][si] = v * siluz[((size_t)b * LSZ + s0 + si) * DIN + d];
        }
    }
    __syncthreads();
    int tp = tid % 96, half = (tid / 96) & 1, kg = tid / 192;
    const float4* WoT4 = (const float4*)WoT;
    const float4* W1T4 = (const float4*)W1T;
    const float4* W2T4 = (const float4*)W2T;
    // ---- out_proj (split d2, quad loads) ----
    {
        float acc[8];
#pragma unroll
        for (int i = 0; i < 8; ++i) acc[i] = 0.f;
        for (int dq = kg * 24; dq < kg * 24 + 24; ++dq) {
            float4 wv = WoT4[dq * 96 + tp];
#pragma unroll
            for (int i = 0; i < 8; ++i) {
                acc[i] = fmaf(wv.x, yl[4 * dq + 0][half * 8 + i],
                         fmaf(wv.y, yl[4 * dq + 1][half * 8 + i],
                         fmaf(wv.z, yl[4 * dq + 2][half * 8 + i],
                         fmaf(wv.w, yl[4 * dq + 3][half * 8 + i], acc[i]))));
            }
        }
#pragma unroll
        for (int i = 0; i < 8; ++i) red[tid][i] = acc[i];
    }
    __syncthreads();
    if (tid < 192) {
#pragma unroll
        for (int i = 0; i < 8; ++i) {
            int si = half * 8 + i;
            xo[tp][si] = x[((size_t)b * CBS + tp) * LSZ + s0 + si] + red[tid][i] + red[tid + 192][i];
        }
    }
    __syncthreads();
    // ---- LN2 ----
    if (tid < 64) {
        int si = tid & 15, g = tid >> 4;
        float s1 = 0.f, s2 = 0.f;
        for (int c = g; c < 96; c += 4) { float v = xo[c][si]; s1 += v; s2 += v * v; }
        s1 += __shfl_xor(s1, 16); s2 += __shfl_xor(s2, 16);
        s1 += __shfl_xor(s1, 32); s2 += __shfl_xor(s2, 32);
        if (g == 0) {
            float mu = s1 * (1.f / 96.f);
            mu16[si] = mu; ir16[si] = rsqrtf(s2 * (1.f / 96.f) - mu * mu + 1e-5f);
        }
    }
    __syncthreads();
#pragma unroll
    for (int it = 0; it < 4; ++it) {
        int e = it * 384 + tid; int si = e / 96, cc = e % 96;
        aa[cc][si] = (xo[cc][si] - mu16[si]) * ir16[si] * l2w[cc] + l2b[cc];
    }
    __syncthreads();
    // ---- MLP fc1 (split j, quad loads) ----
    {
        float acc[8];
#pragma unroll
        for (int i = 0; i < 8; ++i) acc[i] = 0.f;
        for (int jq = kg * 12; jq < kg * 12 + 12; ++jq) {
            float4 wv = W1T4[jq * 96 + tp];
#pragma unroll
            for (int i = 0; i < 8; ++i) {
                acc[i] = fmaf(wv.x, aa[4 * jq + 0][half * 8 + i],
                         fmaf(wv.y, aa[4 * jq + 1][half * 8 + i],
                         fmaf(wv.z, aa[4 * jq + 2][half * 8 + i],
                         fmaf(wv.w, aa[4 * jq + 3][half * 8 + i], acc[i]))));
            }
        }
#pragma unroll
        for (int i = 0; i < 8; ++i) red[tid][i] = acc[i];
    }
    __syncthreads();
    if (tid < 192) {
#pragma unroll
        for (int i = 0; i < 8; ++i) {
            float tv = red[tid][i] + red[tid + 192][i] + b1[tp];
            aa[tp][half * 8 + i] = 0.5f * tv * (1.f + erff(tv * 0.70710678118654752f));
        }
    }
    __syncthreads();
    // ---- MLP fc2 (split j, quad loads) ----
    {
        float acc2[8];
#pragma unroll
        for (int i = 0; i < 8; ++i) acc2[i] = 0.f;
        for (int jq = kg * 12; jq < kg * 12 + 12; ++jq) {
            float4 wv = W2T4[jq * 96 + tp];
#pragma unroll
            for (int i = 0; i < 8; ++i) {
                acc2[i] = fmaf(wv.x, aa[4 * jq + 0][half * 8 + i],
                          fmaf(wv.y, aa[4 * jq + 1][half * 8 + i],
                          fmaf(wv.z, aa[4 * jq + 2][half * 8 + i],
                          fmaf(wv.w, aa[4 * jq + 3][half * 8 + i], acc2[i]))));
            }
        }
#pragma unroll
        for (int i = 0; i < 8; ++i) red[tid][i] = acc2[i];
    }
    __syncthreads();
    if (tid < 192) {
#pragma unroll
        for (int i = 0; i < 8; ++i) {
            float xf = xo[tp][half * 8 + i] + red[tid][i] + red[tid + 192][i] + b2[tp];
            aa[tp][half * 8 + i] = xf * pw[tp];
        }
    }
    __syncthreads();
    if (tid < 64) {
        int si = tid & 15, g = tid >> 4;
        float ss = 0.f;
        for (int c = g; c < 96; c += 4) ss += aa[c][si];
        ss += __shfl_xor(ss, 16);
        ss += __shfl_xor(ss, 32);
        if (g == 0)
            out[(size_t)b * LSZ + s0 + si] = 1.f / (1.f + __expf(-(ss + pb[0])));
    }
}

extern "C" void kernel_launch(void* const* d_in, const int* in_sizes, int n_in,
                              void* d_out, int out_size, void* d_ws, size_t ws_size,
                              hipStream_t stream) {
    const float* x    = (const float*)d_in[0];
    const float* ln1w = (const float*)d_in[1];
    const float* ln1b = (const float*)d_in[2];
    const float* Wp   = (const float*)d_in[3];
    const float* cw   = (const float*)d_in[4];
    const float* cb   = (const float*)d_in[5];
    const float* xpw  = (const float*)d_in[6];
    const float* dtw  = (const float*)d_in[7];
    const float* dtb  = (const float*)d_in[8];
    const float* Alog = (const float*)d_in[9];
    const float* Dsp  = (const float*)d_in[10];
    const float* onw  = (const float*)d_in[11];
    const float* onb  = (const float*)d_in[12];
    const float* Wo   = (const float*)d_in[13];
    const float* l2w  = (const float*)d_in[14];
    const float* l2b  = (const float*)d_in[15];
    const float* W1   = (const float*)d_in[16];
    const float* b1   = (const float*)d_in[17];
    const float* W2   = (const float*)d_in[18];
    const float* b2   = (const float*)d_in[19];
    const float* pw   = (const float*)d_in[20];
    const float* pb   = (const float*)d_in[21];

    float* ws    = (float*)d_ws;
    float* xconv = ws + OFF_XCONV;
    float* ym    = ws + OFF_XCONV;      // reuse: xconv dead after kB
    float* siluz = ws + OFF_SILUZ;
    float* xc    = ws + OFF_XC;
    float* xcT   = ws + OFF_XCT;
    float* BCt   = ws + OFF_BCT;
    float* delta = ws + OFF_DELTA;
    float* yk    = ws + OFF_YK;
    float* wt    = ws + OFF_WT;
    float* WoT   = wt + 36864;
    float* W1T   = wt + 55296;
    float* W2T   = wt + 64512;

    kPrep<<<288, 256, 0, stream>>>(Wp, Wo, W1, W2, wt);
    kA<<<288, 768, 0, stream>>>(x, ln1w, ln1b, wt, xconv, siluz);
    kB<<<192, 512, 0, stream>>>(xconv, cw, cb, xc, xcT);
    kC<<<288, 256, 0, stream>>>(xc, xcT, xpw, dtw, dtb, BCt, delta);
    kD<<<1536, 256, 0, stream>>>(delta, xc, xcT, BCt, Alog, yk);
    kM<<<384, 256, 0, stream>>>(yk, xc, Dsp, ym);
    kEF<<<288, 384, 0, stream>>>(ym, siluz, x, onw, onb, WoT,
                                 l2w, l2b, W1T, b1, W2T, b2, pw, pb, (float*)d_out);
}

// Round 14
// 175.974 us; speedup vs baseline: 1.0581x; 1.0104x over previous
//
#include <hip/hip_runtime.h>
#include <cstdint>

// Problem constants
static constexpr int LSZ = 2304;   // H*W
static constexpr int CBS = 96;     // d_model
static constexpr int DIN = 192;    // d_inner
static constexpr int NST = 16;     // d_state
static constexpr int HHT = 48;
static constexpr int WWD = 48;
static constexpr int CHN = 16;     // chunks for parallel scan
static constexpr int CHL = 144;    // LSZ / CHN  (divisible by 48)

// ---------------- workspace layout (floats) ----------------
static constexpr size_t OFF_XCONV = 0;          // 884736 (reused as ym after kB)
static constexpr size_t OFF_SILUZ = 884736;     // 884736
static constexpr size_t OFF_XC    = 1769472;    // 884736
static constexpr size_t OFF_XCT   = 2654208;    // 884736
static constexpr size_t OFF_BCT   = 3686400;    // 8 * 2304 * 32 = 589824  (B n=0..15, C n=16..31)
static constexpr size_t OFF_DELTA = 4276224;    // 1536 * 2304 = 3538944
static constexpr size_t OFF_YK    = 7815168;    // 3538944
static constexpr size_t OFF_WT    = 11796480;   // 73728

__device__ __forceinline__ float f4get(const float4& v, int i) {
    return i == 0 ? v.x : i == 1 ? v.y : i == 2 ? v.z : v.w;
}

// rotate-reduce sum over each aligned 16-lane group (all lanes get the sum)
__device__ __forceinline__ float rotadd16(float v) {
    int m;
    m = __builtin_amdgcn_update_dpp(0, __float_as_int(v), 0x128, 0xf, 0xf, false); v += __int_as_float(m); // ror8
    m = __builtin_amdgcn_update_dpp(0, __float_as_int(v), 0x124, 0xf, 0xf, false); v += __int_as_float(m); // ror4
    m = __builtin_amdgcn_update_dpp(0, __float_as_int(v), 0x122, 0xf, 0xf, false); v += __int_as_float(m); // ror2
    m = __builtin_amdgcn_update_dpp(0, __float_as_int(v), 0x121, 0xf, 0xf, false); v += __int_as_float(m); // ror1
    return v;
}

// ---------------- prep: weight transposes (quad-interleaved layouts) ----------------
// Wt4 : [c/4][384][4]  (36864)   WoT4: [d2/4][96][4] (18432)
// W1T4: [j/4][96][4]   (9216)    W2T4: [j/4][96][4]  (9216)
__global__ __launch_bounds__(256) void kPrep(const float* __restrict__ Wp,
    const float* __restrict__ Wo, const float* __restrict__ W1,
    const float* __restrict__ W2, float* __restrict__ wt) {
    int e = blockIdx.x * 256 + threadIdx.x;
    if (e < 36864) {
        int cq = e / 1536, rem = e % 1536; int t = rem >> 2, q = rem & 3;
        int c = 4 * cq + q;
        wt[e] = Wp[t * 96 + c];
    } else if (e < 55296) {
        int e2 = e - 36864;
        int dq = e2 / 384, rem = e2 % 384; int tp = rem >> 2, q = rem & 3;
        int d2 = 4 * dq + q;
        wt[e] = Wo[tp * 192 + d2];
    } else if (e < 64512) {
        int e3 = e - 55296;
        int jq = e3 / 384, rem = e3 % 384; int tp = rem >> 2, q = rem & 3;
        int j = 4 * jq + q;
        wt[e] = W1[tp * 96 + j];
    } else if (e < 73728) {
        int e3 = e - 64512;
        int jq = e3 / 384, rem = e3 % 384; int tp = rem >> 2, q = rem & 3;
        int j = 4 * jq + q;
        wt[e] = W2[tp * 96 + j];
    }
}

// ---------------- A: LN1 + in_proj (768 thr, split-c + LDS reduce; wave-parallel LN; quad weights) ----------------
__global__ __launch_bounds__(768) void kA(const float* __restrict__ x,
    const float* __restrict__ ln1w, const float* __restrict__ ln1b,
    const float* __restrict__ Wt, float* __restrict__ xconv, float* __restrict__ siluz) {
    int blk = blockIdx.x; int b = blk / 144; int s0 = (blk % 144) * 16;
    int tid = threadIdx.x;
    __shared__ float xln[96][20];
    __shared__ float redA[384][17];
    __shared__ float mu16[16], ir16[16];
#pragma unroll
    for (int it = 0; it < 2; ++it) {
        int e = it * 768 + tid; int c = e >> 4, si = e & 15;
        xln[c][si] = x[((size_t)b * CBS + c) * LSZ + s0 + si];
    }
    __syncthreads();
    if (tid < 64) {
        int si = tid & 15, g = tid >> 4;
        float s1 = 0.f, s2 = 0.f;
        for (int c = g; c < 96; c += 4) { float v = xln[c][si]; s1 += v; s2 += v * v; }
        s1 += __shfl_xor(s1, 16); s2 += __shfl_xor(s2, 16);
        s1 += __shfl_xor(s1, 32); s2 += __shfl_xor(s2, 32);
        if (g == 0) {
            float mu = s1 * (1.f / 96.f);
            mu16[si] = mu; ir16[si] = rsqrtf(s2 * (1.f / 96.f) - mu * mu + 1e-5f);
        }
    }
    __syncthreads();
#pragma unroll
    for (int it = 0; it < 2; ++it) {
        int e = it * 768 + tid; int c = e >> 4, si = e & 15;
        xln[c][si] = (xln[c][si] - mu16[si]) * ir16[si] * ln1w[c] + ln1b[c];
    }
    __syncthreads();
    int t = tid % 384, cg = tid / 384;
    float acc[16];
#pragma unroll
    for (int i = 0; i < 16; ++i) acc[i] = 0.f;
    const float4* Wt4 = (const float4*)Wt;
    for (int cq = cg * 12; cq < cg * 12 + 12; ++cq) {
        float4 wv = Wt4[cq * 384 + t];
#pragma unroll
        for (int i = 0; i < 16; ++i) {
            acc[i] = fmaf(wv.x, xln[4 * cq + 0][i],
                     fmaf(wv.y, xln[4 * cq + 1][i],
                     fmaf(wv.z, xln[4 * cq + 2][i],
                     fmaf(wv.w, xln[4 * cq + 3][i], acc[i]))));
        }
    }
    if (cg == 1) {
#pragma unroll
        for (int i = 0; i < 16; ++i) redA[t][i] = acc[i];
    }
    __syncthreads();
    if (cg == 0) {
#pragma unroll
        for (int i = 0; i < 16; ++i) acc[i] += redA[t][i];
        if (t < DIN) {
            size_t base = ((size_t)b * DIN + t) * LSZ + s0;
#pragma unroll
            for (int q = 0; q < 4; ++q) {
                float4 v = make_float4(acc[4 * q], acc[4 * q + 1], acc[4 * q + 2], acc[4 * q + 3]);
                *(float4*)(xconv + base + 4 * q) = v;
            }
        } else {
            int tz = t - DIN;
#pragma unroll
            for (int si = 0; si < 16; ++si) {
                float z = acc[si];
                siluz[((size_t)b * LSZ + s0 + si) * DIN + tz] = z / (1.f + __expf(-z));
            }
        }
    }
}

// ---------------- B: depthwise 3x3 conv + bias + SiLU, one block per (b,d) plane ----------------
__global__ __launch_bounds__(256) void kB(const float* __restrict__ xconv,
    const float* __restrict__ cw, const float* __restrict__ cb,
    float* __restrict__ xc, float* __restrict__ xcT) {
    int bd = blockIdx.x;               // b*DIN + d
    int d = bd % DIN;
    int tid = threadIdx.x;
    __shared__ float inp[2304];
    __shared__ float outp[48 * 49];
    const float* src = xconv + (size_t)bd * LSZ;
#pragma unroll
    for (int i = 0; i < 9; ++i) inp[i * 256 + tid] = src[i * 256 + tid];
    float w0 = cw[d * 9 + 0], w1 = cw[d * 9 + 1], w2 = cw[d * 9 + 2];
    float w3 = cw[d * 9 + 3], w4 = cw[d * 9 + 4], w5 = cw[d * 9 + 5];
    float w6 = cw[d * 9 + 6], w7 = cw[d * 9 + 7], w8 = cw[d * 9 + 8];
    float bias = cb[d];
    __syncthreads();
#pragma unroll
    for (int i = 0; i < 9; ++i) {
        int s = i * 256 + tid; int h = s / 48, w = s % 48;
        float acc = bias;
        bool hn = h > 0, hp = h < 47, wn = w > 0, wp = w < 47;
        if (hn) {
            if (wn) acc = fmaf(inp[s - 49], w0, acc);
            acc = fmaf(inp[s - 48], w1, acc);
            if (wp) acc = fmaf(inp[s - 47], w2, acc);
        }
        if (wn) acc = fmaf(inp[s - 1], w3, acc);
        acc = fmaf(inp[s], w4, acc);
        if (wp) acc = fmaf(inp[s + 1], w5, acc);
        if (hp) {
            if (wn) acc = fmaf(inp[s + 47], w6, acc);
            acc = fmaf(inp[s + 48], w7, acc);
            if (wp) acc = fmaf(inp[s + 49], w8, acc);
        }
        float r = acc / (1.f + __expf(-acc));
        xc[(size_t)bd * LSZ + s] = r;
        outp[h * 49 + w] = r;
    }
    __syncthreads();
#pragma unroll
    for (int i = 0; i < 9; ++i) {
        int p = i * 256 + tid;          // p = w*48 + h
        int w = p / 48, h = p % 48;
        xcT[(size_t)bd * LSZ + p] = outp[h * 49 + w];
    }
}

// ---------------- C: x_proj + BCt pack + dt_proj + softplus ----------------
__global__ __launch_bounds__(256) void kC(const float* __restrict__ xc,
    const float* __restrict__ xcT, const float* __restrict__ xpw,
    const float* __restrict__ dtw, const float* __restrict__ dtb,
    float* __restrict__ BCt, float* __restrict__ delta) {
    int blk = blockIdx.x; int lt = blk % 36; int k = (blk / 36) & 3; int b = blk / 144;
    int l0 = lt * 64;
    int bk = b * 4 + k;
    __shared__ float xs[DIN][64];
    __shared__ float stage[64][33];
    __shared__ float dtrL[6][64];
    __shared__ float wsh[DIN * 6];
    __shared__ float bshL[DIN];
    const float* src = ((k & 1) ? xcT : xc) + (size_t)b * DIN * LSZ;
    bool fwd = (k < 2);
    int tid = threadIdx.x;
    for (int e = tid; e < 1152; e += 256) wsh[e] = dtw[k * 1152 + e];
    if (tid < DIN) bshL[tid] = dtb[k * DIN + tid];
#pragma unroll
    for (int i = 0; i < 48; ++i) {
        int e = i * 256 + tid; int d = e >> 6, ll = e & 63;
        int l = l0 + ll; int sl = fwd ? l : (LSZ - 1 - l);
        xs[d][ll] = src[(size_t)d * LSZ + sl];
    }
    __syncthreads();
    int c0 = tid >> 6, ll = tid & 63;
    float acc[10];
#pragma unroll
    for (int j = 0; j < 10; ++j) acc[j] = 0.f;
    for (int d0 = 0; d0 < DIN; d0 += 16) {
        float xv[16];
#pragma unroll
        for (int i = 0; i < 16; ++i) xv[i] = xs[d0 + i][ll];
#pragma unroll
        for (int j = 0; j < 10; ++j) {
            int c = j * 4 + c0;
            if (c < 38) {
                const float4* wr = (const float4*)(xpw + ((size_t)(k * 38 + c)) * DIN + d0);
                float4 q0 = wr[0], q1 = wr[1], q2 = wr[2], q3 = wr[3];
                acc[j] += xv[0] * q0.x + xv[1] * q0.y + xv[2] * q0.z + xv[3] * q0.w
                        + xv[4] * q1.x + xv[5] * q1.y + xv[6] * q1.z + xv[7] * q1.w
                        + xv[8] * q2.x + xv[9] * q2.y + xv[10] * q2.z + xv[11] * q2.w
                        + xv[12] * q3.x + xv[13] * q3.y + xv[14] * q3.z + xv[15] * q3.w;
            }
        }
    }
#pragma unroll
    for (int j = 0; j < 10; ++j) {
        int c = j * 4 + c0;
        if (c < 6) {
            dtrL[c][ll] = acc[j];
        } else if (c < 38) {
            int n2 = (c < 22) ? (c - 6) : (16 + c - 22);
            stage[ll][n2] = acc[j];
        }
    }
    __syncthreads();
    // coalesced write-out: BCt rows l0..l0+63, 32 floats each (contiguous 8KB)
    float* dst = BCt + ((size_t)bk * LSZ + l0) * 32;
#pragma unroll
    for (int it = 0; it < 8; ++it) {
        int e = it * 256 + tid;
        int l = e >> 5, n2 = e & 31;
        dst[e] = stage[l][n2];
    }
    // dt_proj + softplus -> delta
    int dsub = tid >> 6;
    float dr[6];
#pragma unroll
    for (int r = 0; r < 6; ++r) dr[r] = dtrL[r][ll];
    for (int j = 0; j < 48; ++j) {
        int d = j * 4 + dsub;
        float a2 = bshL[d];
#pragma unroll
        for (int r = 0; r < 6; ++r) a2 = fmaf(dr[r], wsh[d * 6 + r], a2);
        float sp = (a2 > 20.f) ? a2 : log1pf(__expf(a2));
        delta[((size_t)bk * DIN + d) * LSZ + l0 + ll] = sp;
    }
}

// ---------------- D: fused 2-pass chunked scan (FROZEN — round-7 exact) ----------------
__global__ __launch_bounds__(256, 4) void kD(const float* __restrict__ delta,
    const float* __restrict__ xc, const float* __restrict__ xcT,
    const float* __restrict__ BCt, const float* __restrict__ A_log, float* __restrict__ yk) {
    int g = blockIdx.x;                 // bk*192 + d
    int tid = threadIdx.x;
    int n = tid & 15; int c = tid >> 4; // chunk 0..15
    int d = g % DIN; int bk = g / DIN; int k = bk & 3; int b = bk >> 2;
    __shared__ float hfinL[256];
    __shared__ float sumdL[16];
    __shared__ float hinL[256];

    float An2 = -__expf(A_log[((size_t)(k * DIN + d)) * NST + n]) * 1.44269504f;
    const float* ub = ((k & 1) ? xcT : xc) + ((size_t)(b * DIN + d)) * LSZ;
    bool fwd = (k < 2);
    int l0 = c * CHL;
    const float* dp = delta + (size_t)g * LSZ + l0;
    const float* up = fwd ? (ub + l0) : (ub + (LSZ - 4) - l0);
    const float* bc = BCt + ((size_t)bk * LSZ + l0) * 32 + n;   // B at +l*32, C at +l*32+16

    // ---- phase 1: chunk-local scan from h=0; record h_final and sum(delta) ----
    float h = 0.f, sd = 0.f;
    for (int j0 = 0; j0 < CHL; j0 += 4) {
        float4 dv = *(const float4*)(dp + j0);
        float4 uv;
        if (fwd) uv = *(const float4*)(up + j0);
        else { float4 tv = *(const float4*)(up - j0); uv = make_float4(tv.w, tv.z, tv.y, tv.x); }
#pragma unroll
        for (int jj = 0; jj < 4; ++jj) {
            float bn = bc[(j0 + jj) * 32];
            float dl = f4get(dv, jj);
            float da = __builtin_amdgcn_exp2f(dl * An2);
            h = fmaf(da, h, dl * f4get(uv, jj) * bn);
            sd += dl;
        }
    }
    hfinL[tid] = h;
    if (n == 0) sumdL[c] = sd;
    __syncthreads();

    // ---- combine: serial prefix over 16 chunks by one 16-lane group ----
    if (tid < 16) {
        float hh = 0.f;
#pragma unroll
        for (int cc = 0; cc < 16; ++cc) {
            hinL[cc * 16 + tid] = hh;
            hh = fmaf(__builtin_amdgcn_exp2f(An2 * sumdL[cc]), hh, hfinL[cc * 16 + tid]);
        }
    }
    __syncthreads();

    // ---- phase 2: re-scan with h_in; lane n keeps y for l%16==n; coalesced stores ----
    h = hinL[tid];
    float* yo = yk + (size_t)g * LSZ + l0 + n;
    for (int m = 0; m < 9; ++m) {
        float ykeep = 0.f;
        for (int q = 0; q < 4; ++q) {
            int j0 = m * 16 + q * 4;
            float4 dv = *(const float4*)(dp + j0);
            float4 uv;
            if (fwd) uv = *(const float4*)(up + j0);
            else { float4 tv = *(const float4*)(up - j0); uv = make_float4(tv.w, tv.z, tv.y, tv.x); }
#pragma unroll
            for (int jj = 0; jj < 4; ++jj) {
                float bn = bc[(j0 + jj) * 32];
                float cn = bc[(j0 + jj) * 32 + 16];
                float dl = f4get(dv, jj);
                float da = __builtin_amdgcn_exp2f(dl * An2);
                h = fmaf(da, h, dl * f4get(uv, jj) * bn);
                float p = rotadd16(h * cn);
                ykeep = (n == q * 4 + jj) ? p : ykeep;
            }
        }
        yo[m * 16] = ykeep;
    }
}

// ---------------- M: cross-merge 4 directions + D*u term -> ym[b][d][s] (48x49 padded LDS) ----------------
__global__ __launch_bounds__(256) void kM(const float* __restrict__ yk,
    const float* __restrict__ xc, const float* __restrict__ Dsp, float* __restrict__ ym) {
    int blk = blockIdx.x;               // b*192 + d
    int b = blk / DIN; int d = blk % DIN;
    int tid = threadIdx.x;
    __shared__ float buf[4][48 * 49];
    float Dsum = Dsp[d] + Dsp[DIN + d] + Dsp[2 * DIN + d] + Dsp[3 * DIN + d];
#pragma unroll
    for (int kk = 0; kk < 4; ++kk) {
        const float* src = yk + ((size_t)((b * 4 + kk) * DIN + d)) * LSZ;
#pragma unroll
        for (int i = 0; i < 9; ++i) {
            int s = i * 256 + tid;
            buf[kk][s + s / 48] = src[s];          // element (h,w) at h*49+w
        }
    }
    __syncthreads();
    const float* xrow = xc + ((size_t)(b * DIN + d)) * LSZ;
    float* dst = ym + ((size_t)blk) * LSZ;
#pragma unroll
    for (int i = 0; i < 9; ++i) {
        int s = i * 256 + tid; int hh = s / 48, ww = s % 48;
        float v0 = buf[0][hh * 49 + ww];
        float v2 = buf[2][(47 - hh) * 49 + (47 - ww)];
        float v1 = buf[1][ww * 49 + hh];
        float v3 = buf[3][(47 - ww) * 49 + (47 - hh)];
        dst[s] = v0 + v2 + v1 + v3 + Dsum * xrow[s];
    }
}

// ---------------- EF: fused epilogue (384 thr; wave-parallel LNs; quad weights) ----------------
__global__ __launch_bounds__(384) void kEF(const float* __restrict__ ym,
    const float* __restrict__ siluz, const float* __restrict__ x,
    const float* __restrict__ onw, const float* __restrict__ onb,
    const float* __restrict__ WoT,
    const float* __restrict__ l2w, const float* __restrict__ l2b,
    const float* __restrict__ W1T, const float* __restrict__ b1,
    const float* __restrict__ W2T, const float* __restrict__ b2,
    const float* __restrict__ pw, const float* __restrict__ pb, float* __restrict__ out) {
    int blk = blockIdx.x; int b = blk / 144; int s0 = (blk % 144) * 16;
    int tid = threadIdx.x;
    __shared__ float yl[DIN][17];
    __shared__ float xo[96][17];
    __shared__ float aa[96][17];
    __shared__ float red[384][9];
    __shared__ float mu16[16], ir16[16];
    // ---- load merged y tile ----
#pragma unroll
    for (int it = 0; it < 8; ++it) {
        int e = it * 384 + tid; int d = e >> 4, si = e & 15;
        yl[d][si] = ym[((size_t)(b * DIN + d)) * LSZ + s0 + si];
    }
    __syncthreads();
    if (tid < 64) {
        int si = tid & 15, g = tid >> 4;
        float s1 = 0.f, s2 = 0.f;
        for (int c = g; c < 192; c += 4) { float v = yl[c][si]; s1 += v; s2 += v * v; }
        s1 += __shfl_xor(s1, 16); s2 += __shfl_xor(s2, 16);
        s1 += __shfl_xor(s1, 32); s2 += __shfl_xor(s2, 32);
        if (g == 0) {
            float mu = s1 * (1.f / 192.f);
            mu16[si] = mu; ir16[si] = rsqrtf(s2 * (1.f / 192.f) - mu * mu + 1e-5f);
        }
    }
    __syncthreads();
    {
        int d = tid % 192, sh = tid / 192;
#pragma unroll
        for (int i = 0; i < 8; ++i) {
            int si = sh * 8 + i;
            float v = yl[d][si];
            v = (v - mu16[si]) * ir16[si] * onw[d] + onb[d];
            yl[d][si] = v * siluz[((size_t)b * LSZ + s0 + si) * DIN + d];
        }
    }
    __syncthreads();
    int tp = tid % 96, half = (tid / 96) & 1, kg = tid / 192;
    const float4* WoT4 = (const float4*)WoT;
    const float4* W1T4 = (const float4*)W1T;
    const float4* W2T4 = (const float4*)W2T;
    // ---- out_proj (split d2, quad loads) ----
    {
        float acc[8];
#pragma unroll
        for (int i = 0; i < 8; ++i) acc[i] = 0.f;
        for (int dq = kg * 24; dq < kg * 24 + 24; ++dq) {
            float4 wv = WoT4[dq * 96 + tp];
#pragma unroll
            for (int i = 0; i < 8; ++i) {
                acc[i] = fmaf(wv.x, yl[4 * dq + 0][half * 8 + i],
                         fmaf(wv.y, yl[4 * dq + 1][half * 8 + i],
                         fmaf(wv.z, yl[4 * dq + 2][half * 8 + i],
                         fmaf(wv.w, yl[4 * dq + 3][half * 8 + i], acc[i]))));
            }
        }
#pragma unroll
        for (int i = 0; i < 8; ++i) red[tid][i] = acc[i];
    }
    __syncthreads();
    if (tid < 192) {
#pragma unroll
        for (int i = 0; i < 8; ++i) {
            int si = half * 8 + i;
            xo[tp][si] = x[((size_t)b * CBS + tp) * LSZ + s0 + si] + red[tid][i] + red[tid + 192][i];
        }
    }
    __syncthreads();
    // ---- LN2 ----
    if (tid < 64) {
        int si = tid & 15, g = tid >> 4;
        float s1 = 0.f, s2 = 0.f;
        for (int c = g; c < 96; c += 4) { float v = xo[c][si]; s1 += v; s2 += v * v; }
        s1 += __shfl_xor(s1, 16); s2 += __shfl_xor(s2, 16);
        s1 += __shfl_xor(s1, 32); s2 += __shfl_xor(s2, 32);
        if (g == 0) {
            float mu = s1 * (1.f / 96.f);
            mu16[si] = mu; ir16[si] = rsqrtf(s2 * (1.f / 96.f) - mu * mu + 1e-5f);
        }
    }
    __syncthreads();
#pragma unroll
    for (int it = 0; it < 4; ++it) {
        int e = it * 384 + tid; int si = e / 96, cc = e % 96;
        aa[cc][si] = (xo[cc][si] - mu16[si]) * ir16[si] * l2w[cc] + l2b[cc];
    }
    __syncthreads();
    // ---- MLP fc1 (split j, quad loads) ----
    {
        float acc[8];
#pragma unroll
        for (int i = 0; i < 8; ++i) acc[i] = 0.f;
        for (int jq = kg * 12; jq < kg * 12 + 12; ++jq) {
            float4 wv = W1T4[jq * 96 + tp];
#pragma unroll
            for (int i = 0; i < 8; ++i) {
                acc[i] = fmaf(wv.x, aa[4 * jq + 0][half * 8 + i],
                         fmaf(wv.y, aa[4 * jq + 1][half * 8 + i],
                         fmaf(wv.z, aa[4 * jq + 2][half * 8 + i],
                         fmaf(wv.w, aa[4 * jq + 3][half * 8 + i], acc[i]))));
            }
        }
#pragma unroll
        for (int i = 0; i < 8; ++i) red[tid][i] = acc[i];
    }
    __syncthreads();
    if (tid < 192) {
#pragma unroll
        for (int i = 0; i < 8; ++i) {
            float tv = red[tid][i] + red[tid + 192][i] + b1[tp];
            aa[tp][half * 8 + i] = 0.5f * tv * (1.f + erff(tv * 0.70710678118654752f));
        }
    }
    __syncthreads();
    // ---- MLP fc2 (split j, quad loads) ----
    {
        float acc2[8];
#pragma unroll
        for (int i = 0; i < 8; ++i) acc2[i] = 0.f;
        for (int jq = kg * 12; jq < kg * 12 + 12; ++jq) {
            float4 wv = W2T4[jq * 96 + tp];
#pragma unroll
            for (int i = 0; i < 8; ++i) {
                acc2[i] = fmaf(wv.x, aa[4 * jq + 0][half * 8 + i],
                          fmaf(wv.y, aa[4 * jq + 1][half * 8 + i],
                          fmaf(wv.z, aa[4 * jq + 2][half * 8 + i],
                          fmaf(wv.w, aa[4 * jq + 3][half * 8 + i], acc2[i]))));
            }
        }
#pragma unroll
        for (int i = 0; i < 8; ++i) red[tid][i] = acc2[i];
    }
    __syncthreads();
    if (tid < 192) {
#pragma unroll
        for (int i = 0; i < 8; ++i) {
            float xf = xo[tp][half * 8 + i] + red[tid][i] + red[tid + 192][i] + b2[tp];
            aa[tp][half * 8 + i] = xf * pw[tp];
        }
    }
    __syncthreads();
    if (tid < 64) {
        int si = tid & 15, g = tid >> 4;
        float ss = 0.f;
        for (int c = g; c < 96; c += 4) ss += aa[c][si];
        ss += __shfl_xor(ss, 16);
        ss += __shfl_xor(ss, 32);
        if (g == 0)
            out[(size_t)b * LSZ + s0 + si] = 1.f / (1.f + __expf(-(ss + pb[0])));
    }
}

extern "C" void kernel_launch(void* const* d_in, const int* in_sizes, int n_in,
                              void* d_out, int out_size, void* d_ws, size_t ws_size,
                              hipStream_t stream) {
    const float* x    = (const float*)d_in[0];
    const float* ln1w = (const float*)d_in[1];
    const float* ln1b = (const float*)d_in[2];
    const float* Wp   = (const float*)d_in[3];
    const float* cw   = (const float*)d_in[4];
    const float* cb   = (const float*)d_in[5];
    const float* xpw  = (const float*)d_in[6];
    const float* dtw  = (const float*)d_in[7];
    const float* dtb  = (const float*)d_in[8];
    const float* Alog = (const float*)d_in[9];
    const float* Dsp  = (const float*)d_in[10];
    const float* onw  = (const float*)d_in[11];
    const float* onb  = (const float*)d_in[12];
    const float* Wo   = (const float*)d_in[13];
    const float* l2w  = (const float*)d_in[14];
    const float* l2b  = (const float*)d_in[15];
    const float* W1   = (const float*)d_in[16];
    const float* b1   = (const float*)d_in[17];
    const float* W2   = (const float*)d_in[18];
    const float* b2   = (const float*)d_in[19];
    const float* pw   = (const float*)d_in[20];
    const float* pb   = (const float*)d_in[21];

    float* ws    = (float*)d_ws;
    float* xconv = ws + OFF_XCONV;
    float* ym    = ws + OFF_XCONV;      // reuse: xconv dead after kB
    float* siluz = ws + OFF_SILUZ;
    float* xc    = ws + OFF_XC;
    float* xcT   = ws + OFF_XCT;
    float* BCt   = ws + OFF_BCT;
    float* delta = ws + OFF_DELTA;
    float* yk    = ws + OFF_YK;
    float* wt    = ws + OFF_WT;
    float* WoT   = wt + 36864;
    float* W1T   = wt + 55296;
    float* W2T   = wt + 64512;

    kPrep<<<288, 256, 0, stream>>>(Wp, Wo, W1, W2, wt);
    kA<<<288, 768, 0, stream>>>(x, ln1w, ln1b, wt, xconv, siluz);
    kB<<<384, 256, 0, stream>>>(xconv, cw, cb, xc, xcT);
    kC<<<288, 256, 0, stream>>>(xc, xcT, xpw, dtw, dtb, BCt, delta);
    kD<<<1536, 256, 0, stream>>>(delta, xc, xcT, BCt, Alog, yk);
    kM<<<384, 256, 0, stream>>>(yk, xc, Dsp, ym);
    kEF<<<288, 384, 0, stream>>>(ym, siluz, x, onw, onb, WoT,
                                 l2w, l2b, W1T, b1, W2T, b2, pw, pb, (float*)d_out);
}